// Round 1
// baseline (154.122 us; speedup 1.0000x reference)
//
#include <hip/hip_runtime.h>
#include <hip/hip_bf16.h>

#define N_SPK 2048
#define M_UTT 10
#define D_DIM 256
#define NM (N_SPK * M_UTT)   // 20480
#define CS 2                 // column split for k_gemm
#define NCH (N_SPK / CS / 64)  // 16 chunks of 64 cols per block

typedef __attribute__((ext_vector_type(8))) short bf16x8_t;
typedef __attribute__((ext_vector_type(4))) float f32x4_t;

__device__ __forceinline__ short f2bf(float x) {
  __hip_bfloat16 h = __float2bfloat16(x);
  return *reinterpret_cast<short*>(&h);
}

// swizzled LDS short-index for a [64][256]-short tile:
// element (r, 16B-chunk kc) lives at r*256 + ((kc ^ (r&7))*8)
__device__ __forceinline__ int swz(int r, int kc) {
  return r * 256 + ((kc ^ (r & 7)) << 3);
}

// ---------------- K1: centroids = l2norm(mean_m(emb)) ----------------
__global__ __launch_bounds__(256) void k_centroid(const float* __restrict__ emb,
                                                  float* __restrict__ cent_f,
                                                  __hip_bfloat16* __restrict__ cent_b) {
  int n = blockIdx.x, d = threadIdx.x;
  const float* p = emb + (size_t)n * (M_UTT * D_DIM) + d;
  float s = 0.f;
#pragma unroll
  for (int m = 0; m < M_UTT; ++m) s += p[m * D_DIM];
  float ss = s * s;
#pragma unroll
  for (int o = 32; o >= 1; o >>= 1) ss += __shfl_xor(ss, o, 64);
  __shared__ float red[4];
  int wid = threadIdx.x >> 6, lane = threadIdx.x & 63;
  if (lane == 0) red[wid] = ss;
  __syncthreads();
  float tot = red[0] + red[1] + red[2] + red[3];
  // centroid = sum / max(||sum||, 10*eps)  (== mean / max(||mean||, eps))
  float inv = 1.0f / fmaxf(sqrtf(tot), 1e-11f);
  float v = s * inv;
  cent_f[n * D_DIM + d] = v;
  cent_b[n * D_DIM + d] = __float2bfloat16(v);
}

// ---------------- K2: per-row rnorm + positive-pair dot ----------------
__global__ __launch_bounds__(256) void k_rows(const float* __restrict__ emb,
                                              const float* __restrict__ cent_f,
                                              float* __restrict__ rnorm,
                                              float* __restrict__ dvals) {
  int wid = threadIdx.x >> 6, lane = threadIdx.x & 63;
  int g = blockIdx.x * 4 + wid;  // one row per wave
  const float4* e4 = (const float4*)(emb + (size_t)g * D_DIM);
  float4 e = e4[lane];
  int n = g / M_UTT;
  const float4* c4 = (const float4*)(cent_f + (size_t)n * D_DIM);
  float4 c = c4[lane];
  float ss = e.x * e.x + e.y * e.y + e.z * e.z + e.w * e.w;
  float dt = e.x * c.x + e.y * c.y + e.z * c.z + e.w * c.w;
#pragma unroll
  for (int o = 32; o >= 1; o >>= 1) {
    ss += __shfl_xor(ss, o, 64);
    dt += __shfl_xor(dt, o, 64);
  }
  if (lane == 0) {
    float rn = 1.0f / fmaxf(sqrtf(ss), 1e-12f);
    rnorm[g] = rn;
    dvals[g] = dt * rn;  // cos(e_nm, c_n)
  }
}

// ---------------- K3: fused GEMM + exp row-sums ----------------
// sim = |w|*cos + b ; accumulate exp(sim - (|w|+b)) = exp(|w|*(cos-1))
__global__ __launch_bounds__(256) void k_gemm(const float* __restrict__ emb,
                                              const __hip_bfloat16* __restrict__ cent_b,
                                              const float* __restrict__ rnorm,
                                              float* __restrict__ rowsum,
                                              const float* __restrict__ wp) {
  __shared__ short As[64 * 256];
  __shared__ short Bs[64 * 256];
  const float aw = fabsf(wp[0]);
  const int tid = threadIdx.x;
  const int lane = tid & 63, wid = tid >> 6;
  const int l15 = lane & 15, lhi = lane >> 4;
  const int wr = wid >> 1, wc = wid & 1;  // 2x2 wave grid, 32x32 tile each
  const int row0 = blockIdx.x * 64;
  const int col0 = blockIdx.y * (N_SPK / CS);

  // ---- stage A (normalize + bf16 convert), swizzled ----
#pragma unroll
  for (int j = 0; j < 8; ++j) {
    int cid = j * 256 + tid;
    int r = cid >> 5, kc = cid & 31;
    int grow = row0 + r;
    const float4* src = (const float4*)(emb + (size_t)grow * D_DIM + (kc << 3));
    float4 f0 = src[0], f1 = src[1];
    float rn = rnorm[grow];
    bf16x8_t v;
    v[0] = f2bf(f0.x * rn); v[1] = f2bf(f0.y * rn);
    v[2] = f2bf(f0.z * rn); v[3] = f2bf(f0.w * rn);
    v[4] = f2bf(f1.x * rn); v[5] = f2bf(f1.y * rn);
    v[6] = f2bf(f1.z * rn); v[7] = f2bf(f1.w * rn);
    *(bf16x8_t*)&As[swz(r, kc)] = v;
  }

  float rowacc[2][4] = {};  // [m-frag][reg] partial exp-sums

  for (int ch = 0; ch < NCH; ++ch) {
    __syncthreads();  // previous chunk's reads done (covers A staging on ch=0)
    int cb = col0 + ch * 64;
#pragma unroll
    for (int j = 0; j < 8; ++j) {
      int cid = j * 256 + tid;
      int r = cid >> 5, kc = cid & 31;
      const bf16x8_t* src =
          (const bf16x8_t*)((const short*)cent_b + (size_t)(cb + r) * D_DIM + (kc << 3));
      *(bf16x8_t*)&Bs[swz(r, kc)] = *src;
    }
    __syncthreads();

    f32x4_t acc[2][2];
#pragma unroll
    for (int m = 0; m < 2; ++m)
#pragma unroll
      for (int nn = 0; nn < 2; ++nn) acc[m][nn] = (f32x4_t){0.f, 0.f, 0.f, 0.f};

#pragma unroll
    for (int kk = 0; kk < 8; ++kk) {
      bf16x8_t a0 = *(const bf16x8_t*)&As[swz(32 * wr + l15,      (kk << 2) + lhi)];
      bf16x8_t a1 = *(const bf16x8_t*)&As[swz(32 * wr + 16 + l15, (kk << 2) + lhi)];
      bf16x8_t b0 = *(const bf16x8_t*)&Bs[swz(32 * wc + l15,      (kk << 2) + lhi)];
      bf16x8_t b1 = *(const bf16x8_t*)&Bs[swz(32 * wc + 16 + l15, (kk << 2) + lhi)];
      acc[0][0] = __builtin_amdgcn_mfma_f32_16x16x32_bf16(a0, b0, acc[0][0], 0, 0, 0);
      acc[0][1] = __builtin_amdgcn_mfma_f32_16x16x32_bf16(a0, b1, acc[0][1], 0, 0, 0);
      acc[1][0] = __builtin_amdgcn_mfma_f32_16x16x32_bf16(a1, b0, acc[1][0], 0, 0, 0);
      acc[1][1] = __builtin_amdgcn_mfma_f32_16x16x32_bf16(a1, b1, acc[1][1], 0, 0, 0);
    }

#pragma unroll
    for (int m = 0; m < 2; ++m)
#pragma unroll
      for (int r4 = 0; r4 < 4; ++r4)
        rowacc[m][r4] += __expf(aw * (acc[m][0][r4] - 1.0f)) +
                         __expf(aw * (acc[m][1][r4] - 1.0f));
  }

  // reduce across the 16 lanes holding the same output row (bits 0..3 of lane)
#pragma unroll
  for (int mask = 1; mask < 16; mask <<= 1)
#pragma unroll
    for (int m = 0; m < 2; ++m)
#pragma unroll
      for (int r4 = 0; r4 < 4; ++r4)
        rowacc[m][r4] += __shfl_xor(rowacc[m][r4], mask, 64);

  if (l15 == 0) {
#pragma unroll
    for (int m = 0; m < 2; ++m)
#pragma unroll
      for (int r4 = 0; r4 < 4; ++r4)
        atomicAdd(&rowsum[row0 + 32 * wr + 16 * m + 4 * lhi + r4], rowacc[m][r4]);
  }
}

// ---------------- K4: final reduction -> scalar loss ----------------
// loss = mean(log(rowsum)) + |w| * (1 - mean(dvals))   (b cancels)
__global__ __launch_bounds__(256) void k_final(const float* __restrict__ rowsum,
                                               const float* __restrict__ dvals,
                                               const float* __restrict__ wp,
                                               float* __restrict__ out) {
  float s = 0.f, ds = 0.f;
  for (int i = threadIdx.x; i < NM; i += 256) {
    s += logf(rowsum[i]);
    ds += dvals[i];
  }
#pragma unroll
  for (int o = 32; o >= 1; o >>= 1) {
    s += __shfl_xor(s, o, 64);
    ds += __shfl_xor(ds, o, 64);
  }
  __shared__ float rs[4], rd[4];
  int wid = threadIdx.x >> 6, lane = threadIdx.x & 63;
  if (lane == 0) { rs[wid] = s; rd[wid] = ds; }
  __syncthreads();
  if (threadIdx.x == 0) {
    float S = rs[0] + rs[1] + rs[2] + rs[3];
    float Dd = rd[0] + rd[1] + rd[2] + rd[3];
    float aw = fabsf(wp[0]);
    out[0] = S / (float)NM + aw * (1.0f - Dd / (float)NM);
  }
}

extern "C" void kernel_launch(void* const* d_in, const int* in_sizes, int n_in,
                              void* d_out, int out_size, void* d_ws, size_t ws_size,
                              hipStream_t stream) {
  const float* emb = (const float*)d_in[0];
  const float* wp  = (const float*)d_in[1];
  float* out = (float*)d_out;

  char* ws = (char*)d_ws;
  float* rowsum = (float*)(ws);                       // 20480 f32 (81920 B)
  float* cent_f = (float*)(ws + 82048);               // 2 MB
  __hip_bfloat16* cent_b = (__hip_bfloat16*)(ws + 82048 + 2097152);  // 1 MB
  float* rnorm  = (float*)(ws + 82048 + 2097152 + 1048576);          // 80 KB
  float* dvals  = (float*)(ws + 82048 + 2097152 + 1048576 + 81920);  // 80 KB

  hipMemsetAsync(rowsum, 0, NM * sizeof(float), stream);
  k_centroid<<<N_SPK, 256, 0, stream>>>(emb, cent_f, cent_b);
  k_rows<<<NM / 4, 256, 0, stream>>>(emb, cent_f, rnorm, dvals);
  k_gemm<<<dim3(NM / 64, CS), 256, 0, stream>>>(emb, cent_b, rnorm, rowsum, wp);
  k_final<<<1, 256, 0, stream>>>(rowsum, dvals, wp, out);
}

// Round 2
// 126.488 us; speedup vs baseline: 1.2185x; 1.2185x over previous
//
#include <hip/hip_runtime.h>
#include <hip/hip_bf16.h>

#define N_SPK 2048
#define M_UTT 10
#define D_DIM 256
#define NM (N_SPK * M_UTT)   // 20480

typedef __attribute__((ext_vector_type(8))) short bf16x8_t;
typedef __attribute__((ext_vector_type(16))) float f32x16_t;

__device__ __forceinline__ short f2bf(float x) {
  __hip_bfloat16 h = __float2bfloat16(x);
  return *reinterpret_cast<short*>(&h);
}

// ---------------- K1: centroids = l2norm(mean_m(emb)) ----------------
// Writes cent_f (f32, for K2's pos-dot) and Bf: centroids laid out in
// 32x32x16 MFMA A-operand fragment order:
//   Bf[((cg*16 + ks)*64 + l)*8 + e] = cent[cg*32 + (l&31)][ks*16 + (l>>5)*8 + e]
__global__ __launch_bounds__(256) void k_centroid(const float* __restrict__ emb,
                                                  float* __restrict__ cent_f,
                                                  __hip_bfloat16* __restrict__ Bf) {
  int n = blockIdx.x, d = threadIdx.x;
  const float* p = emb + (size_t)n * (M_UTT * D_DIM) + d;
  float s = 0.f;
#pragma unroll
  for (int m = 0; m < M_UTT; ++m) s += p[m * D_DIM];
  float ss = s * s;
#pragma unroll
  for (int o = 32; o >= 1; o >>= 1) ss += __shfl_xor(ss, o, 64);
  __shared__ float red[4];
  int wid = threadIdx.x >> 6, lane = threadIdx.x & 63;
  if (lane == 0) red[wid] = ss;
  __syncthreads();
  float tot = red[0] + red[1] + red[2] + red[3];
  float inv = 1.0f / fmaxf(sqrtf(tot), 1e-11f);  // == mean/max(||mean||,1e-12)
  float v = s * inv;
  cent_f[n * D_DIM + d] = v;
  int idx = (((n >> 5) * 16 + (d >> 4)) * 64 + ((d >> 3) & 1) * 32 + (n & 31)) * 8 + (d & 7);
  Bf[idx] = __float2bfloat16(v);
}

// ---------------- K2: normalized bf16 rows + pos-dot + rowsum init ----------------
__global__ __launch_bounds__(256) void k_prep(const float* __restrict__ emb,
                                              const float* __restrict__ cent_f,
                                              __hip_bfloat16* __restrict__ embn,
                                              float* __restrict__ dvals,
                                              float* __restrict__ rowsum) {
  int wid = threadIdx.x >> 6, lane = threadIdx.x & 63;
  int g = blockIdx.x * 4 + wid;  // one row per wave
  const float4 e = ((const float4*)(emb + (size_t)g * D_DIM))[lane];
  int n = g / M_UTT;
  const float4 c = ((const float4*)(cent_f + (size_t)n * D_DIM))[lane];
  float ss = e.x * e.x + e.y * e.y + e.z * e.z + e.w * e.w;
  float dt = e.x * c.x + e.y * c.y + e.z * c.z + e.w * c.w;
#pragma unroll
  for (int o = 32; o >= 1; o >>= 1) {
    ss += __shfl_xor(ss, o, 64);
    dt += __shfl_xor(dt, o, 64);
  }
  float rn = 1.0f / fmaxf(sqrtf(ss), 1e-12f);
  short4 v;
  v.x = f2bf(e.x * rn); v.y = f2bf(e.y * rn);
  v.z = f2bf(e.z * rn); v.w = f2bf(e.w * rn);
  ((short4*)embn)[(size_t)g * 64 + lane] = v;
  if (lane == 0) {
    dvals[g] = dt * rn;   // cos(e_nm, c_n)
    rowsum[g] = 0.f;      // init for K3's atomics
  }
}

// ---------------- K3: fused GEMM + exp row-sums ----------------
// Swapped operands: D = cent_frag * emb_frag -> lane holds ONE emb-row
// (l&31) per rg across regs => in-lane exp-sum, 1 shfl, 4 atomics/lane.
// A (cent) frags come straight from L2 (frag-ordered Bf, coalesced 1KB/wave).
// B (emb rows) staged once in LDS via global_load_lds, XOR-swizzled source.
// No barriers in the K-loop.
__global__ __launch_bounds__(512, 2) void k_gemm(const __hip_bfloat16* __restrict__ embn,
                                                 const __hip_bfloat16* __restrict__ Bf,
                                                 float* __restrict__ rowsum,
                                                 const float* __restrict__ wp) {
  __shared__ short As[128 * 256];  // 64KB: 128 rows x 256 K, chunk-swizzled
  const float aw = fabsf(wp[0]);
  const int tid = threadIdx.x;
  const int lane = tid & 63, w = tid >> 6;
  const int l31 = lane & 31, lh = lane >> 5;
  const int row0 = blockIdx.x * 128;

  // ---- stage A: linear LDS dest, pre-swizzled global source (kc ^ (r&7)) ----
  {
    const short* srcbase = (const short*)embn;
#pragma unroll
    for (int p = 0; p < 8; ++p) {
      int r = p * 16 + w * 2 + lh;  // LDS row this lane feeds
      const short* src = srcbase + (size_t)(row0 + r) * D_DIM + ((l31 ^ (r & 7)) << 3);
      __builtin_amdgcn_global_load_lds(
          (const __attribute__((address_space(1))) void*)src,
          (__attribute__((address_space(3))) void*)&As[p * 4096 + w * 512],
          16, 0, 0);
    }
  }
  asm volatile("s_waitcnt vmcnt(0)" ::: "memory");
  __syncthreads();

  const int cg = blockIdx.y * 16 + w * 2;  // this wave's centroid col-group
  const bf16x8_t* bp = (const bf16x8_t*)Bf;

  f32x16_t acc[4][2];
#pragma unroll
  for (int rg = 0; rg < 4; ++rg)
#pragma unroll
    for (int ci = 0; ci < 2; ++ci)
#pragma unroll
      for (int r = 0; r < 16; ++r) acc[rg][ci][r] = 0.f;

#pragma unroll
  for (int ks = 0; ks < 16; ++ks) {
    bf16x8_t b0 = bp[(size_t)(cg * 16 + ks) * 64 + lane];
    bf16x8_t b1 = bp[(size_t)((cg + 1) * 16 + ks) * 64 + lane];
    const int sw = ((ks * 2 + lh) ^ (l31 & 7)) << 3;  // row&7 == l31&7 for all rg
    bf16x8_t e0 = *(const bf16x8_t*)&As[l31 * 256 + sw];
    bf16x8_t e1 = *(const bf16x8_t*)&As[(l31 + 32) * 256 + sw];
    bf16x8_t e2 = *(const bf16x8_t*)&As[(l31 + 64) * 256 + sw];
    bf16x8_t e3 = *(const bf16x8_t*)&As[(l31 + 96) * 256 + sw];
    acc[0][0] = __builtin_amdgcn_mfma_f32_32x32x16_bf16(b0, e0, acc[0][0], 0, 0, 0);
    acc[0][1] = __builtin_amdgcn_mfma_f32_32x32x16_bf16(b1, e0, acc[0][1], 0, 0, 0);
    acc[1][0] = __builtin_amdgcn_mfma_f32_32x32x16_bf16(b0, e1, acc[1][0], 0, 0, 0);
    acc[1][1] = __builtin_amdgcn_mfma_f32_32x32x16_bf16(b1, e1, acc[1][1], 0, 0, 0);
    acc[2][0] = __builtin_amdgcn_mfma_f32_32x32x16_bf16(b0, e2, acc[2][0], 0, 0, 0);
    acc[2][1] = __builtin_amdgcn_mfma_f32_32x32x16_bf16(b1, e2, acc[2][1], 0, 0, 0);
    acc[3][0] = __builtin_amdgcn_mfma_f32_32x32x16_bf16(b0, e3, acc[3][0], 0, 0, 0);
    acc[3][1] = __builtin_amdgcn_mfma_f32_32x32x16_bf16(b1, e3, acc[3][1], 0, 0, 0);
  }

  // epilogue: per lane, rows rg*32 + l31; cols (cent) spread over regs & lh.
  // exp(|w|*(cos-1)) summed in-lane, then lh-halves combined via one shfl.
#pragma unroll
  for (int rg = 0; rg < 4; ++rg) {
    float s = 0.f;
#pragma unroll
    for (int ci = 0; ci < 2; ++ci)
#pragma unroll
      for (int r = 0; r < 16; ++r)
        s += __expf(fmaf(aw, acc[rg][ci][r], -aw));
    s += __shfl_xor(s, 32, 64);
    if (lane < 32) atomicAdd(&rowsum[row0 + rg * 32 + lane], s);
  }
}

// ---------------- K4: final reduction -> scalar loss ----------------
// loss = mean(log(rowsum)) + |w| * (1 - mean(dvals))   (b cancels)
__global__ __launch_bounds__(256) void k_final(const float* __restrict__ rowsum,
                                               const float* __restrict__ dvals,
                                               const float* __restrict__ wp,
                                               float* __restrict__ out) {
  float s = 0.f, ds = 0.f;
  for (int i = threadIdx.x; i < NM; i += 256) {
    s += logf(rowsum[i]);
    ds += dvals[i];
  }
#pragma unroll
  for (int o = 32; o >= 1; o >>= 1) {
    s += __shfl_xor(s, o, 64);
    ds += __shfl_xor(ds, o, 64);
  }
  __shared__ float rs[4], rd[4];
  int wid = threadIdx.x >> 6, lane = threadIdx.x & 63;
  if (lane == 0) { rs[wid] = s; rd[wid] = ds; }
  __syncthreads();
  if (threadIdx.x == 0) {
    float S = rs[0] + rs[1] + rs[2] + rs[3];
    float Dd = rd[0] + rd[1] + rd[2] + rd[3];
    float aw = fabsf(wp[0]);
    out[0] = S / (float)NM + aw * (1.0f - Dd / (float)NM);
  }
}

extern "C" void kernel_launch(void* const* d_in, const int* in_sizes, int n_in,
                              void* d_out, int out_size, void* d_ws, size_t ws_size,
                              hipStream_t stream) {
  const float* emb = (const float*)d_in[0];
  const float* wp  = (const float*)d_in[1];
  float* out = (float*)d_out;

  char* ws = (char*)d_ws;
  float* rowsum = (float*)(ws);                            // 80 KB
  float* dvals  = (float*)(ws + 131072);                   // 80 KB
  float* cent_f = (float*)(ws + 262144);                   // 2 MB
  __hip_bfloat16* Bf   = (__hip_bfloat16*)(ws + 2621440);  // 1 MB frag-ordered
  __hip_bfloat16* embn = (__hip_bfloat16*)(ws + 4194304);  // 10 MB normalized rows

  k_centroid<<<N_SPK, 256, 0, stream>>>(emb, cent_f, Bf);
  k_prep<<<NM / 4, 256, 0, stream>>>(emb, cent_f, embn, dvals, rowsum);
  k_gemm<<<dim3(NM / 128, 4), 512, 0, stream>>>(embn, Bf, rowsum, wp);
  k_final<<<1, 256, 0, stream>>>(rowsum, dvals, wp, out);
}

// Round 3
// 110.035 us; speedup vs baseline: 1.4007x; 1.1495x over previous
//
#include <hip/hip_runtime.h>
#include <hip/hip_bf16.h>

#define N_SPK 2048
#define M_UTT 10
#define D_DIM 256
#define NM (N_SPK * M_UTT)   // 20480

typedef __attribute__((ext_vector_type(8))) short bf16x8_t;
typedef __attribute__((ext_vector_type(16))) float f32x16_t;

__device__ __forceinline__ short f2bf(float x) {
  __hip_bfloat16 h = __float2bfloat16(x);
  return *reinterpret_cast<short*>(&h);
}

// ---------------- K1: fused prep ----------------
// One block per speaker n (2048 blocks x 256 threads, d = tid):
//  - centroid v = sum_m(e) / max(||sum||, 1e-11)  (== mean/max(||mean||,1e-12))
//  - Bf: centroid in 32x32x16 MFMA A-frag order
//  - per-utterance rn = 1/max(||e_m||,1e-12), dvals = cos(e_m, v)
//  - embn = bf16(e_m * rn)  (row-major [NM][256])
//  - zero rowsum rows, zero out[0]
__global__ __launch_bounds__(256) void k_prep(const float* __restrict__ emb,
                                              __hip_bfloat16* __restrict__ Bf,
                                              __hip_bfloat16* __restrict__ embn,
                                              float* __restrict__ dvals,
                                              float* __restrict__ rowsum,
                                              float* __restrict__ out) {
  const int n = blockIdx.x, d = threadIdx.x;
  const int wid = d >> 6, lane = d & 63;
  const float* p = emb + (size_t)n * (M_UTT * D_DIM) + d;

  float e[M_UTT];
  float s = 0.f;
#pragma unroll
  for (int m = 0; m < M_UTT; ++m) { e[m] = p[m * D_DIM]; s += e[m]; }

  // centroid norm (block reduce of s^2)
  float ss = s * s;
#pragma unroll
  for (int o = 32; o >= 1; o >>= 1) ss += __shfl_xor(ss, o, 64);
  __shared__ float redc[4];
  if (lane == 0) redc[wid] = ss;
  __syncthreads();
  float tot = redc[0] + redc[1] + redc[2] + redc[3];
  float inv = 1.0f / fmaxf(sqrtf(tot), 1e-11f);
  float v = s * inv;

  // Bf fragment layout (identical to verified round-2 layout)
  int idx = (((n >> 5) * 16 + (d >> 4)) * 64 + ((d >> 3) & 1) * 32 + (n & 31)) * 8 + (d & 7);
  Bf[idx] = __float2bfloat16(v);

  // per-utterance ||e||^2 and e.v (block reduces)
  __shared__ float redm[M_UTT][2][4];
#pragma unroll
  for (int m = 0; m < M_UTT; ++m) {
    float a = e[m] * e[m], bb = e[m] * v;
#pragma unroll
    for (int o = 32; o >= 1; o >>= 1) {
      a += __shfl_xor(a, o, 64);
      bb += __shfl_xor(bb, o, 64);
    }
    if (lane == 0) { redm[m][0][wid] = a; redm[m][1][wid] = bb; }
  }
  __syncthreads();
  __shared__ float rnb[M_UTT];
  if (d < M_UTT) {
    float ssm = redm[d][0][0] + redm[d][0][1] + redm[d][0][2] + redm[d][0][3];
    float dtm = redm[d][1][0] + redm[d][1][1] + redm[d][1][2] + redm[d][1][3];
    float rn = 1.0f / fmaxf(sqrtf(ssm), 1e-12f);
    rnb[d] = rn;
    dvals[n * M_UTT + d] = dtm * rn;   // cos(e_m, centroid_n)
    rowsum[n * M_UTT + d] = 0.f;
  }
  if (n == 0 && d == 0) out[0] = 0.f;
  __syncthreads();

  short* eo = (short*)embn + (size_t)n * (M_UTT * D_DIM) + d;
#pragma unroll
  for (int m = 0; m < M_UTT; ++m) eo[m * D_DIM] = f2bf(e[m] * rnb[m]);
}

// ---------------- K2: fused GEMM + exp row-sums ----------------
// Swapped operands: D = cent_frag * emb_frag -> each lane owns emb-rows.
// A (cent) frags straight from L2 (frag-ordered Bf); B (emb) staged once in
// LDS via global_load_lds with XOR-pre-swizzled source. No barriers in the
// K-loop; explicit 1-deep prefetch of B (global) and A-frags (LDS).
__global__ __launch_bounds__(512, 2) void k_gemm(const __hip_bfloat16* __restrict__ embn,
                                                 const __hip_bfloat16* __restrict__ Bf,
                                                 float* __restrict__ rowsum,
                                                 const float* __restrict__ wp) {
  __shared__ short As[128 * 256];  // 64KB: 128 rows x 256 K, chunk-swizzled
  const float aw = fabsf(wp[0]);
  const int tid = threadIdx.x;
  const int lane = tid & 63, w = tid >> 6;
  const int l31 = lane & 31, lh = lane >> 5;
  const int row0 = blockIdx.x * 128;

  // ---- stage: linear LDS dest, pre-swizzled global source (kc ^ (r&7)) ----
  {
    const short* srcbase = (const short*)embn;
#pragma unroll
    for (int p = 0; p < 8; ++p) {
      int r = p * 16 + w * 2 + lh;  // LDS row this lane feeds
      const short* src = srcbase + (size_t)(row0 + r) * D_DIM + ((l31 ^ (r & 7)) << 3);
      __builtin_amdgcn_global_load_lds(
          (const __attribute__((address_space(1))) void*)src,
          (__attribute__((address_space(3))) void*)&As[p * 4096 + w * 512],
          16, 0, 0);
    }
  }
  asm volatile("s_waitcnt vmcnt(0)" ::: "memory");
  __syncthreads();

  const int cg = blockIdx.y * 16 + w * 2;  // this wave's centroid col-group
  const bf16x8_t* b0p = (const bf16x8_t*)Bf + (size_t)(cg * 16) * 64 + lane;
  const bf16x8_t* b1p = (const bf16x8_t*)Bf + (size_t)((cg + 1) * 16) * 64 + lane;

  f32x16_t acc[4][2];
#pragma unroll
  for (int rg = 0; rg < 4; ++rg)
#pragma unroll
    for (int ci = 0; ci < 2; ++ci)
#pragma unroll
      for (int r = 0; r < 16; ++r) acc[rg][ci][r] = 0.f;

  // prefetch iteration 0
  bf16x8_t cb0 = b0p[0], cb1 = b1p[0];
  bf16x8_t e0, e1, e2, e3;
  {
    const int sw = (lh ^ (l31 & 7)) << 3;
    e0 = *(const bf16x8_t*)&As[l31 * 256 + sw];
    e1 = *(const bf16x8_t*)&As[(l31 + 32) * 256 + sw];
    e2 = *(const bf16x8_t*)&As[(l31 + 64) * 256 + sw];
    e3 = *(const bf16x8_t*)&As[(l31 + 96) * 256 + sw];
  }

#pragma unroll
  for (int ks = 0; ks < 16; ++ks) {
    bf16x8_t nb0, nb1, f0, f1, f2, f3;
    if (ks < 15) {
      nb0 = b0p[(ks + 1) * 64];
      nb1 = b1p[(ks + 1) * 64];
      const int sw = (((ks + 1) * 2 + lh) ^ (l31 & 7)) << 3;
      f0 = *(const bf16x8_t*)&As[l31 * 256 + sw];
      f1 = *(const bf16x8_t*)&As[(l31 + 32) * 256 + sw];
      f2 = *(const bf16x8_t*)&As[(l31 + 64) * 256 + sw];
      f3 = *(const bf16x8_t*)&As[(l31 + 96) * 256 + sw];
    }
    acc[0][0] = __builtin_amdgcn_mfma_f32_32x32x16_bf16(cb0, e0, acc[0][0], 0, 0, 0);
    acc[0][1] = __builtin_amdgcn_mfma_f32_32x32x16_bf16(cb1, e0, acc[0][1], 0, 0, 0);
    acc[1][0] = __builtin_amdgcn_mfma_f32_32x32x16_bf16(cb0, e1, acc[1][0], 0, 0, 0);
    acc[1][1] = __builtin_amdgcn_mfma_f32_32x32x16_bf16(cb1, e1, acc[1][1], 0, 0, 0);
    acc[2][0] = __builtin_amdgcn_mfma_f32_32x32x16_bf16(cb0, e2, acc[2][0], 0, 0, 0);
    acc[2][1] = __builtin_amdgcn_mfma_f32_32x32x16_bf16(cb1, e2, acc[2][1], 0, 0, 0);
    acc[3][0] = __builtin_amdgcn_mfma_f32_32x32x16_bf16(cb0, e3, acc[3][0], 0, 0, 0);
    acc[3][1] = __builtin_amdgcn_mfma_f32_32x32x16_bf16(cb1, e3, acc[3][1], 0, 0, 0);
    cb0 = nb0; cb1 = nb1;
    e0 = f0; e1 = f1; e2 = f2; e3 = f3;
  }

  // epilogue: per lane, rows rg*32 + l31; exp-sum in-lane, 1 shfl, atomics.
#pragma unroll
  for (int rg = 0; rg < 4; ++rg) {
    float s = 0.f;
#pragma unroll
    for (int ci = 0; ci < 2; ++ci)
#pragma unroll
      for (int r = 0; r < 16; ++r)
        s += __expf(fmaf(aw, acc[rg][ci][r], -aw));
    s += __shfl_xor(s, 32, 64);
    if (lane < 32) atomicAdd(&rowsum[row0 + rg * 32 + lane], s);
  }
}

// ---------------- K3: final reduction -> scalar loss ----------------
// out = sum_r [log(rowsum_r) + aw*(1 - dval_r)] / NM   (b cancels)
__global__ __launch_bounds__(256) void k_final(const float* __restrict__ rowsum,
                                               const float* __restrict__ dvals,
                                               const float* __restrict__ wp,
                                               float* __restrict__ out) {
  const float aw = fabsf(wp[0]);
  int base = blockIdx.x * 512 + threadIdx.x;
  float c = 0.f;
#pragma unroll
  for (int j = 0; j < 2; ++j) {
    int r = base + j * 256;
    c += logf(rowsum[r]) + aw * (1.0f - dvals[r]);
  }
#pragma unroll
  for (int o = 32; o >= 1; o >>= 1) c += __shfl_xor(c, o, 64);
  __shared__ float rs[4];
  int wid = threadIdx.x >> 6, lane = threadIdx.x & 63;
  if (lane == 0) rs[wid] = c;
  __syncthreads();
  if (threadIdx.x == 0)
    atomicAdd(out, (rs[0] + rs[1] + rs[2] + rs[3]) * (1.0f / (float)NM));
}

extern "C" void kernel_launch(void* const* d_in, const int* in_sizes, int n_in,
                              void* d_out, int out_size, void* d_ws, size_t ws_size,
                              hipStream_t stream) {
  const float* emb = (const float*)d_in[0];
  const float* wp  = (const float*)d_in[1];
  float* out = (float*)d_out;

  char* ws = (char*)d_ws;
  float* rowsum = (float*)(ws);                            // 80 KB @ 0
  float* dvals  = (float*)(ws + (128 << 10));              // 80 KB @ 128K
  __hip_bfloat16* Bf   = (__hip_bfloat16*)(ws + (1 << 20)); // 1 MB @ 1M (frag order)
  __hip_bfloat16* embn = (__hip_bfloat16*)(ws + (2 << 20)); // 10 MB @ 2M (normalized)

  k_prep<<<N_SPK, 256, 0, stream>>>(emb, Bf, embn, dvals, rowsum, out);
  k_gemm<<<dim3(NM / 128, 4), 512, 0, stream>>>(embn, Bf, rowsum, wp);
  k_final<<<NM / 512, 256, 0, stream>>>(rowsum, dvals, wp, out);
}